// Round 6
// baseline (482.464 us; speedup 1.0000x reference)
//
#include <hip/hip_runtime.h>
#include <hip/hip_bf16.h>

// textPCNN R6: t-split blocks for occupancy.
//  K0 convert_convw: conv_w fp32->bf16 into ws (1.23 MB)
//  K1 pcnn_conv: block = (sentence n, t-half): gathers 66 x-rows (56 KB LDS,
//     2 blocks/CU -> 4 waves/SIMD, phase overlap across blocks), conv GEMM
//     (mfma 16x16x32 bf16, acc[4][4]=64 VGPR), pools raw acc over 3 segments,
//     writes partial maxima (3x512 fp32) to ws.
//  K2 pcnn_out: combine halves, bias+tanh (monotonic => after max), 1536x53 GEMM.
// R5 post-mortem: 332us @ MfmaUtil 21%, occupancy 23% (1 block/CU, 2 waves/
// SIMD) -- TLP-starved serial phases; ~135us of bench time is fixed harness
// overhead outside the kernels.

#define XSTRIDE 424     // LDS x-row stride in bf16 elems (848 B = 53 short8)
#define LPV 126
#define NC 53

typedef __attribute__((ext_vector_type(8))) short short8;
typedef __attribute__((ext_vector_type(4))) float floatx4;

__device__ __forceinline__ unsigned short f2bf_rne(float x) {
    unsigned u = __float_as_uint(x);
    u += 0x7fffu + ((u >> 16) & 1u);   // round-to-nearest-even (inputs finite)
    return (unsigned short)(u >> 16);
}

__global__ void __launch_bounds__(1024)
convert_convw(const float* __restrict__ src, unsigned short* __restrict__ dst) {
    int i = blockIdx.x * 1024 + threadIdx.x;
    if (i < 512 * 1200) dst[i] = f2bf_rne(src[i]);
}

// K1: grid 2048 = (n, half). Conv rows t in [64*half, 64*half+64).
extern "C" __global__ void __launch_bounds__(512, 4)
pcnn_conv(const int* __restrict__ tokens, const int* __restrict__ pf1,
          const int* __restrict__ pf2, const int* __restrict__ epos,
          const float* __restrict__ wordvec,
          const float* __restrict__ pf1e,
          const float* __restrict__ pf2e,
          const unsigned short* __restrict__ convwb,   // bf16 [512][1200] in ws
          float* __restrict__ pooled)                  // [2048][3][512] in ws
{
    extern __shared__ char smem[];
    unsigned short* xl = (unsigned short*)smem;        // 66*424 ush = 55968 B
    int* idx = (int*)(smem + 55968);                   // 3*66 ints = 792 B

    const int n    = blockIdx.x >> 1;
    const int half = blockIdx.x & 1;
    const int tid  = threadIdx.x;
    const int lane = tid & 63;
    const int wv   = tid >> 6;
    const int nrows = half ? 64 : 66;   // real x rows in this tile

    if (tid < 66 && 64 * half + tid < 128) {
        int base = n * 128 + 64 * half + tid;
        idx[tid]       = tokens[base];
        idx[66 + tid]  = pf1[base];
        idx[132 + tid] = pf2[base];
    }
    if (half) {   // zero LDS rows 64,65 (global 128,129)
        const short8 z8 = {0, 0, 0, 0, 0, 0, 0, 0};
        short8* dst8 = (short8*)xl;
        for (int i = tid; i < 106; i += 512)
            dst8[64 * 53 + i] = z8;     // rows 64,65 = 106 contiguous short8
    }
    __syncthreads();

    // ---- flat gather + fp32->bf16, all iterations independent ----
    {
        const float2* wv2 = (const float2*)wordvec;    // 150 float2 per row
        const float2* p12 = (const float2*)pf1e;       // 25 float2 per row
        const float2* p22 = (const float2*)pf2e;
        #pragma unroll 4
        for (int i = tid; i < nrows * 150; i += 512) { // word part
            int row = i / 150, c = i - row * 150;
            float2 v = wv2[(long)idx[row] * 150 + c];
            *(ushort2*)(xl + row * XSTRIDE + 2 * c) =
                make_ushort2(f2bf_rne(v.x), f2bf_rne(v.y));
        }
        #pragma unroll 4
        for (int i = tid; i < nrows * 25; i += 512) {  // pf1 + pf2 parts
            int row = i / 25, c = i - row * 25;
            float2 v = p12[idx[66 + row] * 25 + c];
            *(ushort2*)(xl + row * XSTRIDE + 300 + 2 * c) =
                make_ushort2(f2bf_rne(v.x), f2bf_rne(v.y));
            float2 w = p22[idx[132 + row] * 25 + c];
            *(ushort2*)(xl + row * XSTRIDE + 350 + 2 * c) =
                make_ushort2(f2bf_rne(w.x), f2bf_rne(w.y));
        }
    }
    __syncthreads();

    // ---- conv GEMM: C[64 t x 512 f]; wave wv owns f in [64wv, 64wv+64) ----
    // A[t][k] = xl[t + k/400][k%400]; B^T row f (bf16 in ws). No barriers.
    const int col = lane & 15;   // A row-in-tile / B row-in-tile / C col
    const int kq  = lane >> 4;   // k-quad: k offset 8*kq; C row = 4*kq + r

    const floatx4 fz = {0.f, 0.f, 0.f, 0.f};
    floatx4 acc[4][4];   // [mt][jt]
    #pragma unroll
    for (int mt = 0; mt < 4; ++mt)
        #pragma unroll
        for (int jt = 0; jt < 4; ++jt) acc[mt][jt] = fz;

    int ck   = kq * 8;                       // k mod 400 for this lane
    int aoff = col * XSTRIDE + kq * 8;       // elem offset of A frag (row mt=0)
    const unsigned short* bptr = convwb + (wv * 64 + col) * 1200 + kq * 8;

    #pragma unroll 1
    for (int kt = 0; kt < 37; ++kt) {        // K = 37*32 + 16 remainder
        short8 a[4];
        #pragma unroll
        for (int mt = 0; mt < 4; ++mt)
            a[mt] = *(const short8*)(xl + aoff + mt * (16 * XSTRIDE));
        #pragma unroll
        for (int jt = 0; jt < 4; ++jt) {
            short8 b = *(const short8*)(bptr + jt * (16 * 1200));
            #pragma unroll
            for (int mt = 0; mt < 4; ++mt)
                acc[mt][jt] = __builtin_amdgcn_mfma_f32_16x16x32_bf16(
                    a[mt], b, acc[mt][jt], 0, 0, 0);
        }
        ck += 32; aoff += 32; bptr += 32;
        if (ck >= 400) { ck -= 400; aoff += XSTRIDE - 400; }
    }
    {   // remainder k0=1184..1199: only kq<2 lanes carry real k
        const short8 z8 = {0, 0, 0, 0, 0, 0, 0, 0};
        short8 a[4];
        #pragma unroll
        for (int mt = 0; mt < 4; ++mt)
            a[mt] = (kq < 2) ? *(const short8*)(xl + aoff + mt * (16 * XSTRIDE))
                             : z8;
        #pragma unroll
        for (int jt = 0; jt < 4; ++jt) {
            short8 b = (kq < 2) ? *(const short8*)(bptr + jt * (16 * 1200)) : z8;
            #pragma unroll
            for (int mt = 0; mt < 4; ++mt)
                acc[mt][jt] = __builtin_amdgcn_mfma_f32_16x16x32_bf16(
                    a[mt], b, acc[mt][jt], 0, 0, 0);
        }
    }

    // ---- pool raw acc over 3 segments (partial, this t-half) ----
    const int p1 = epos[2 * n], p2 = epos[2 * n + 1];
    const int tbase = 64 * half;
    float* pw = pooled + (size_t)blockIdx.x * 1536;
    #pragma unroll
    for (int jt = 0; jt < 4; ++jt) {
        float m0 = -1e30f, m1 = -1e30f, m2 = -1e30f;
        #pragma unroll
        for (int mt = 0; mt < 4; ++mt) {
            #pragma unroll
            for (int r = 0; r < 4; ++r) {
                int t = tbase + mt * 16 + kq * 4 + r;   // global conv row
                float v = acc[mt][jt][r];
                if (t < LPV) {
                    if (t <= p1) m0 = fmaxf(m0, v);
                    if (t >= p1 && t <= p2) m1 = fmaxf(m1, v);
                    if (t >= p2) m2 = fmaxf(m2, v);
                }
            }
        }
        // lanes sharing col differ in kq (xor 16, 32): reduce t-coverage
        m0 = fmaxf(m0, __shfl_xor(m0, 16)); m0 = fmaxf(m0, __shfl_xor(m0, 32));
        m1 = fmaxf(m1, __shfl_xor(m1, 16)); m1 = fmaxf(m1, __shfl_xor(m1, 32));
        m2 = fmaxf(m2, __shfl_xor(m2, 16)); m2 = fmaxf(m2, __shfl_xor(m2, 32));
        if (kq == 0) {
            int f = wv * 64 + jt * 16 + col;
            pw[f]        = m0;     // may be -1e30 if segment misses this half
            pw[512 + f]  = m1;
            pw[1024 + f] = m2;
        }
    }
}

// K2: combine halves, bias+tanh, out GEMM. grid 1024, 256 threads.
extern "C" __global__ void __launch_bounds__(256)
pcnn_out(const float* __restrict__ pooled,
         const float* __restrict__ convb,
         const float* __restrict__ outw,
         const float* __restrict__ outb,
         float* __restrict__ out)
{
    __shared__ float feat[1536];
    __shared__ float red[256];
    const int n = blockIdx.x, tid = threadIdx.x;
    const float* h0 = pooled + (size_t)(2 * n) * 1536;
    const float* h1 = h0 + 1536;
    #pragma unroll
    for (int i = tid; i < 1536; i += 256) {
        int f = i & 511, s = i >> 9;
        float m = fmaxf(h0[i], h1[i]);
        // tanh monotonic: max(tanh(x+b)) == tanh(max(x)+b); segments nonempty
        feat[f * 3 + s] = tanhf(m + convb[f]);
    }
    __syncthreads();
    {
        int c = tid & 63, chunk = tid >> 6;   // 4 chunks x 384 j
        float partial = 0.f;
        if (c < NC) {
            int j0 = chunk * 384;
            #pragma unroll 4
            for (int j = j0; j < j0 + 384; ++j)
                partial += feat[j] * outw[j * 53 + c];
        }
        red[tid] = partial;
        __syncthreads();
        if (tid < NC) {
            float s = outb[tid];
            #pragma unroll
            for (int ch = 0; ch < 4; ++ch) s += red[ch * 64 + tid];
            out[n * 53 + tid] = s;
        }
    }
}

extern "C" void kernel_launch(void* const* d_in, const int* in_sizes, int n_in,
                              void* d_out, int out_size, void* d_ws, size_t ws_size,
                              hipStream_t stream) {
    (void)in_sizes; (void)n_in; (void)ws_size; (void)out_size;
    const int* tokens = (const int*)d_in[0];
    const int* pf1    = (const int*)d_in[1];
    const int* pf2    = (const int*)d_in[2];
    const int* epos   = (const int*)d_in[3];
    const float* wordvec = (const float*)d_in[4];
    const float* pf1e    = (const float*)d_in[5];
    const float* pf2e    = (const float*)d_in[6];
    const float* convw   = (const float*)d_in[7];
    const float* convb   = (const float*)d_in[8];
    const float* outw    = (const float*)d_in[9];
    const float* outb    = (const float*)d_in[10];
    float* out = (float*)d_out;

    // ws: [0, 1228800) convwb bf16; [1228800, +12582912) pooled fp32
    unsigned short* convwb = (unsigned short*)d_ws;
    float* pooled = (float*)((char*)d_ws + 1228800);

    convert_convw<<<dim3(600), dim3(1024), 0, stream>>>(convw, convwb);

    const size_t lds_bytes = 55968 + 792;   // 56760 -> 2 blocks/CU
    pcnn_conv<<<dim3(2048), dim3(512), lds_bytes, stream>>>(
        tokens, pf1, pf2, epos, wordvec, pf1e, pf2e, convwb, pooled);

    pcnn_out<<<dim3(1024), dim3(256), 0, stream>>>(
        pooled, convb, outw, outb, out);
}

// Round 7
// 479.464 us; speedup vs baseline: 1.0063x; 1.0063x over previous
//
#include <hip/hip_runtime.h>
#include <hip/hip_bf16.h>

// textPCNN R7: wave-staggered K-loop to break lockstep convoying.
//  K0 convert_convw: conv_w fp32->bf16 into ws (1.23 MB)
//  K1 pcnn_conv: block = (sentence, t-half), 56 KB LDS -> 2 blocks/CU,
//     4 waves/SIMD. Wave wv starts its kt-loop at kt=(wv*37)>>3 and wraps:
//     at any instant the 8 waves hit different B k-regions / LDS rows and
//     their MFMA bursts interleave (R6: identical streams -> all waves
//     queue loads together, then fight for the MFMA pipe together ->
//     MfmaUtil stuck at 22% regardless of occupancy).
//  K2 pcnn_out: combine halves, bias+tanh, 1536x53 GEMM.

#define XSTRIDE 424     // LDS x-row stride in bf16 elems (848 B = 53 short8)
#define LPV 126
#define NC 53

typedef __attribute__((ext_vector_type(8))) short short8;
typedef __attribute__((ext_vector_type(4))) float floatx4;

__device__ __forceinline__ unsigned short f2bf_rne(float x) {
    unsigned u = __float_as_uint(x);
    u += 0x7fffu + ((u >> 16) & 1u);   // round-to-nearest-even (inputs finite)
    return (unsigned short)(u >> 16);
}

__global__ void __launch_bounds__(1024)
convert_convw(const float* __restrict__ src, unsigned short* __restrict__ dst) {
    int i = blockIdx.x * 1024 + threadIdx.x;
    if (i < 512 * 1200) dst[i] = f2bf_rne(src[i]);
}

// K1: grid 2048 = (n, half). Conv rows t in [64*half, 64*half+64).
extern "C" __global__ void __launch_bounds__(512, 4)
pcnn_conv(const int* __restrict__ tokens, const int* __restrict__ pf1,
          const int* __restrict__ pf2, const int* __restrict__ epos,
          const float* __restrict__ wordvec,
          const float* __restrict__ pf1e,
          const float* __restrict__ pf2e,
          const unsigned short* __restrict__ convwb,   // bf16 [512][1200] in ws
          float* __restrict__ pooled)                  // [2048][3][512] in ws
{
    extern __shared__ char smem[];
    unsigned short* xl = (unsigned short*)smem;        // 66*424 ush = 55968 B
    int* idx = (int*)(smem + 55968);                   // 3*66 ints = 792 B

    const int n    = blockIdx.x >> 1;
    const int half = blockIdx.x & 1;
    const int tid  = threadIdx.x;
    const int lane = tid & 63;
    const int wv   = tid >> 6;
    const int nrows = half ? 64 : 66;   // real x rows in this tile

    if (tid < 66 && 64 * half + tid < 128) {
        int base = n * 128 + 64 * half + tid;
        idx[tid]       = tokens[base];
        idx[66 + tid]  = pf1[base];
        idx[132 + tid] = pf2[base];
    }
    if (half) {   // zero LDS rows 64,65 (global 128,129)
        const short8 z8 = {0, 0, 0, 0, 0, 0, 0, 0};
        short8* dst8 = (short8*)xl;
        for (int i = tid; i < 106; i += 512)
            dst8[64 * 53 + i] = z8;     // rows 64,65 = 106 contiguous short8
    }
    __syncthreads();

    // ---- flat gather + fp32->bf16, all iterations independent ----
    {
        const float2* wv2 = (const float2*)wordvec;    // 150 float2 per row
        const float2* p12 = (const float2*)pf1e;       // 25 float2 per row
        const float2* p22 = (const float2*)pf2e;
        #pragma unroll 4
        for (int i = tid; i < nrows * 150; i += 512) { // word part
            int row = i / 150, c = i - row * 150;
            float2 v = wv2[(long)idx[row] * 150 + c];
            *(ushort2*)(xl + row * XSTRIDE + 2 * c) =
                make_ushort2(f2bf_rne(v.x), f2bf_rne(v.y));
        }
        #pragma unroll 4
        for (int i = tid; i < nrows * 25; i += 512) {  // pf1 + pf2 parts
            int row = i / 25, c = i - row * 25;
            float2 v = p12[idx[66 + row] * 25 + c];
            *(ushort2*)(xl + row * XSTRIDE + 300 + 2 * c) =
                make_ushort2(f2bf_rne(v.x), f2bf_rne(v.y));
            float2 w = p22[idx[132 + row] * 25 + c];
            *(ushort2*)(xl + row * XSTRIDE + 350 + 2 * c) =
                make_ushort2(f2bf_rne(w.x), f2bf_rne(w.y));
        }
    }
    __syncthreads();

    // ---- conv GEMM: C[64 t x 512 f]; wave wv owns f in [64wv, 64wv+64) ----
    // A[t][k] = xl[t + k/400][k%400]; B^T row f (bf16 in ws). K-loop start
    // staggered per wave: kt0 = (wv*37)>>3, wrapping at 37.
    const int col = lane & 15;   // A row-in-tile / B row-in-tile / C col
    const int kq  = lane >> 4;   // k-quad: k offset 8*kq; C row = 4*kq + r

    const floatx4 fz = {0.f, 0.f, 0.f, 0.f};
    floatx4 acc[4][4];   // [mt][jt]
    #pragma unroll
    for (int mt = 0; mt < 4; ++mt)
        #pragma unroll
        for (int jt = 0; jt < 4; ++jt) acc[mt][jt] = fz;

    const unsigned short* brow = convwb + (wv * 64 + col) * 1200 + kq * 8;

    const int s = (wv * 37) >> 3;            // stagger: 0,4,9,13,18,23,27,32
    int k0   = s * 32 + kq * 8;              // this lane's starting k
    int row0 = (k0 >= 400) + (k0 >= 800);    // x-row offset (conv tap)
    int ck   = k0 - 400 * row0;              // k mod 400
    int aoff = (col + row0) * XSTRIDE + ck;  // elem offset of A frag (mt=0)
    const unsigned short* bptr = brow + s * 32;
    int ktl = s;                             // logical kt

    #pragma unroll 1
    for (int i = 0; i < 37; ++i) {           // K = 37*32 + 16 remainder
        short8 a[4];
        #pragma unroll
        for (int mt = 0; mt < 4; ++mt)
            a[mt] = *(const short8*)(xl + aoff + mt * (16 * XSTRIDE));
        #pragma unroll
        for (int jt = 0; jt < 4; ++jt) {
            short8 b = *(const short8*)(bptr + jt * (16 * 1200));
            #pragma unroll
            for (int mt = 0; mt < 4; ++mt)
                acc[mt][jt] = __builtin_amdgcn_mfma_f32_16x16x32_bf16(
                    a[mt], b, acc[mt][jt], 0, 0, 0);
        }
        ++ktl;
        if (ktl == 37) {                     // wrap to kt = 0 (wave-uniform)
            ktl  = 0;
            ck   = kq * 8;
            aoff = col * XSTRIDE + kq * 8;
            bptr = brow;
        } else {
            ck += 32; aoff += 32; bptr += 32;
            if (ck >= 400) { ck -= 400; aoff += XSTRIDE - 400; }
        }
    }
    {   // remainder k0=1184..1199 (row 2): only kq<2 lanes carry real k
        const short8 z8 = {0, 0, 0, 0, 0, 0, 0, 0};
        int aoffr = (col + 2) * XSTRIDE + 384 + kq * 8;
        const unsigned short* bpr = brow + 1184;
        short8 a[4];
        #pragma unroll
        for (int mt = 0; mt < 4; ++mt)
            a[mt] = (kq < 2) ? *(const short8*)(xl + aoffr + mt * (16 * XSTRIDE))
                             : z8;
        #pragma unroll
        for (int jt = 0; jt < 4; ++jt) {
            short8 b = (kq < 2) ? *(const short8*)(bpr + jt * (16 * 1200)) : z8;
            #pragma unroll
            for (int mt = 0; mt < 4; ++mt)
                acc[mt][jt] = __builtin_amdgcn_mfma_f32_16x16x32_bf16(
                    a[mt], b, acc[mt][jt], 0, 0, 0);
        }
    }

    // ---- pool raw acc over 3 segments (partial, this t-half) ----
    const int p1 = epos[2 * n], p2 = epos[2 * n + 1];
    const int tbase = 64 * half;
    float* pw = pooled + (size_t)blockIdx.x * 1536;
    #pragma unroll
    for (int jt = 0; jt < 4; ++jt) {
        float m0 = -1e30f, m1 = -1e30f, m2 = -1e30f;
        #pragma unroll
        for (int mt = 0; mt < 4; ++mt) {
            #pragma unroll
            for (int r = 0; r < 4; ++r) {
                int t = tbase + mt * 16 + kq * 4 + r;   // global conv row
                float v = acc[mt][jt][r];
                if (t < LPV) {
                    if (t <= p1) m0 = fmaxf(m0, v);
                    if (t >= p1 && t <= p2) m1 = fmaxf(m1, v);
                    if (t >= p2) m2 = fmaxf(m2, v);
                }
            }
        }
        // lanes sharing col differ in kq (xor 16, 32): reduce t-coverage
        m0 = fmaxf(m0, __shfl_xor(m0, 16)); m0 = fmaxf(m0, __shfl_xor(m0, 32));
        m1 = fmaxf(m1, __shfl_xor(m1, 16)); m1 = fmaxf(m1, __shfl_xor(m1, 32));
        m2 = fmaxf(m2, __shfl_xor(m2, 16)); m2 = fmaxf(m2, __shfl_xor(m2, 32));
        if (kq == 0) {
            int f = wv * 64 + jt * 16 + col;
            pw[f]        = m0;     // may be -1e30 if segment misses this half
            pw[512 + f]  = m1;
            pw[1024 + f] = m2;
        }
    }
}

// K2: combine halves, bias+tanh, out GEMM. grid 1024, 256 threads.
extern "C" __global__ void __launch_bounds__(256)
pcnn_out(const float* __restrict__ pooled,
         const float* __restrict__ convb,
         const float* __restrict__ outw,
         const float* __restrict__ outb,
         float* __restrict__ out)
{
    __shared__ float feat[1536];
    __shared__ float red[256];
    const int n = blockIdx.x, tid = threadIdx.x;
    const float* h0 = pooled + (size_t)(2 * n) * 1536;
    const float* h1 = h0 + 1536;
    #pragma unroll
    for (int i = tid; i < 1536; i += 256) {
        int f = i & 511, s = i >> 9;
        float m = fmaxf(h0[i], h1[i]);
        // tanh monotonic: max(tanh(x+b)) == tanh(max(x)+b); segments nonempty
        feat[f * 3 + s] = tanhf(m + convb[f]);
    }
    __syncthreads();
    {
        int c = tid & 63, chunk = tid >> 6;   // 4 chunks x 384 j
        float partial = 0.f;
        if (c < NC) {
            int j0 = chunk * 384;
            #pragma unroll 4
            for (int j = j0; j < j0 + 384; ++j)
                partial += feat[j] * outw[j * 53 + c];
        }
        red[tid] = partial;
        __syncthreads();
        if (tid < NC) {
            float s = outb[tid];
            #pragma unroll
            for (int ch = 0; ch < 4; ++ch) s += red[ch * 64 + tid];
            out[n * 53 + tid] = s;
        }
    }
}

extern "C" void kernel_launch(void* const* d_in, const int* in_sizes, int n_in,
                              void* d_out, int out_size, void* d_ws, size_t ws_size,
                              hipStream_t stream) {
    (void)in_sizes; (void)n_in; (void)ws_size; (void)out_size;
    const int* tokens = (const int*)d_in[0];
    const int* pf1    = (const int*)d_in[1];
    const int* pf2    = (const int*)d_in[2];
    const int* epos   = (const int*)d_in[3];
    const float* wordvec = (const float*)d_in[4];
    const float* pf1e    = (const float*)d_in[5];
    const float* pf2e    = (const float*)d_in[6];
    const float* convw   = (const float*)d_in[7];
    const float* convb   = (const float*)d_in[8];
    const float* outw    = (const float*)d_in[9];
    const float* outb    = (const float*)d_in[10];
    float* out = (float*)d_out;

    // ws: [0, 1228800) convwb bf16; [1228800, +12582912) pooled fp32
    unsigned short* convwb = (unsigned short*)d_ws;
    float* pooled = (float*)((char*)d_ws + 1228800);

    convert_convw<<<dim3(600), dim3(1024), 0, stream>>>(convw, convwb);

    const size_t lds_bytes = 55968 + 792;   // 56760 -> 2 blocks/CU
    pcnn_conv<<<dim3(2048), dim3(512), lds_bytes, stream>>>(
        tokens, pf1, pf2, epos, wordvec, pf1e, pf2e, convwb, pooled);

    pcnn_out<<<dim3(1024), dim3(256), 0, stream>>>(
        pooled, convb, outw, outb, out);
}